// Round 5
// baseline (489.584 us; speedup 1.0000x reference)
//
#include <hip/hip_runtime.h>
#include <hip/hip_bf16.h>

// ---------- helpers ----------

__device__ __forceinline__ unsigned short f2bf(float f) {
    unsigned u = __float_as_uint(f);
    unsigned r = u + 0x7fffu + ((u >> 16) & 1u);
    return (unsigned short)(r >> 16);
}

typedef __bf16 bf16_t;
typedef bf16_t bf16x8 __attribute__((ext_vector_type(8)));
typedef float f32x4 __attribute__((ext_vector_type(4)));

typedef const __attribute__((address_space(1))) unsigned int* gptr_t;
typedef __attribute__((address_space(3))) unsigned int* lptr_t;

__device__ __forceinline__ void gload_lds16(const void* g, void* l) {
    __builtin_amdgcn_global_load_lds((gptr_t)g, (lptr_t)l, 16, 0, 0);
}

// ---------- kernel 1: column-wise max of |x| ----------
__global__ void colmax_kernel(const float* __restrict__ src, int rows, int cols,
                              unsigned int* __restrict__ dst, int rows_per_block) {
    int c = (blockIdx.x * blockDim.x + threadIdx.x) * 4;
    if (c >= cols) return;
    int r0 = blockIdx.y * rows_per_block;
    int r1 = min(r0 + rows_per_block, rows);
    float m0 = 0.f, m1 = 0.f, m2 = 0.f, m3 = 0.f;
    const float* p = src + (size_t)r0 * cols + c;
    for (int r = r0; r < r1; ++r, p += cols) {
        float4 v = *(const float4*)p;
        m0 = fmaxf(m0, fabsf(v.x));
        m1 = fmaxf(m1, fabsf(v.y));
        m2 = fmaxf(m2, fabsf(v.z));
        m3 = fmaxf(m3, fabsf(v.w));
    }
    atomicMax(dst + c + 0, __float_as_uint(m0));
    atomicMax(dst + c + 1, __float_as_uint(m1));
    atomicMax(dst + c + 2, __float_as_uint(m2));
    atomicMax(dst + c + 3, __float_as_uint(m3));
}

// ---------- kernel 1b: fused column-max of |W| + W -> bf16 ----------
__global__ void wmaxconv_kernel(const float* __restrict__ W, unsigned int* __restrict__ mw,
                                unsigned short* __restrict__ Wb, int rows, int cols,
                                int rows_per_block) {
    int c = (blockIdx.x * blockDim.x + threadIdx.x) * 4;
    if (c >= cols) return;
    int r0 = blockIdx.y * rows_per_block;
    int r1 = min(r0 + rows_per_block, rows);
    float m0 = 0.f, m1 = 0.f, m2 = 0.f, m3 = 0.f;
    const float* p = W + (size_t)r0 * cols + c;
    unsigned short* q = Wb + (size_t)r0 * cols + c;
    for (int r = r0; r < r1; ++r, p += cols, q += cols) {
        float4 v = *(const float4*)p;
        ushort4 o;
        o.x = f2bf(v.x); o.y = f2bf(v.y); o.z = f2bf(v.z); o.w = f2bf(v.w);
        *(ushort4*)q = o;
        m0 = fmaxf(m0, fabsf(v.x));
        m1 = fmaxf(m1, fabsf(v.y));
        m2 = fmaxf(m2, fabsf(v.z));
        m3 = fmaxf(m3, fabsf(v.w));
    }
    atomicMax(mw + c + 0, __float_as_uint(m0));
    atomicMax(mw + c + 1, __float_as_uint(m1));
    atomicMax(mw + c + 2, __float_as_uint(m2));
    atomicMax(mw + c + 3, __float_as_uint(m3));
}

// ---------- kernel 2: s = sqrt(max_act / clip(max_w, EPS)) ----------
__global__ void s_kernel(const unsigned int* __restrict__ ma,
                         const unsigned int* __restrict__ mw,
                         float* __restrict__ s, int n) {
    int i = blockIdx.x * blockDim.x + threadIdx.x;
    if (i < n) {
        float a = __uint_as_float(ma[i]);
        float w = fmaxf(__uint_as_float(mw[i]), 1e-8f);
        s[i] = sqrtf(a / w);
    }
}

// ---------- kernel 3: 2:4 prune of (x/s), emit bf16(x)*mask ----------
__global__ void prune_kernel(const float* __restrict__ x, const float* __restrict__ s,
                             unsigned short* __restrict__ xsp, size_t ngroups, int cols) {
    size_t g = (size_t)blockIdx.x * blockDim.x + threadIdx.x;
    size_t stride = (size_t)gridDim.x * blockDim.x;
    for (; g < ngroups; g += stride) {
        size_t e = g * 4;
        int cb = (int)(e & (size_t)(cols - 1));
        float4 v = *(const float4*)(x + e);
        float4 sv = *(const float4*)(s + cb);
        float a0 = fabsf(v.x / sv.x);
        float a1 = fabsf(v.y / sv.y);
        float a2 = fabsf(v.z / sv.z);
        float a3 = fabsf(v.w / sv.w);
        int r0 = 0, r1 = 0, r2 = 0, r3 = 0;
        if (a1 > a0) r0++; else r1++;
        if (a2 > a0) r0++; else r2++;
        if (a3 > a0) r0++; else r3++;
        if (a2 > a1) r1++; else r2++;
        if (a3 > a1) r1++; else r3++;
        if (a3 > a2) r2++; else r3++;
        ushort4 o;
        o.x = (r0 < 2) ? f2bf(v.x) : (unsigned short)0;
        o.y = (r1 < 2) ? f2bf(v.y) : (unsigned short)0;
        o.z = (r2 < 2) ? f2bf(v.z) : (unsigned short)0;
        o.w = (r3 < 2) ? f2bf(v.w) : (unsigned short)0;
        *(ushort4*)(xsp + e) = o;
    }
}

// ---------- kernel 5: 256x256 8-phase bf16 B^T GEMM (m201-fidelity sync) ----------
// C[m,n] = sum_k A[m,k]*B[n,k]. 8 waves (2Mx4N), BK=64, 128 KiB LDS dbuf,
// quadrant phases (0,0)->(0,1)->(1,1)->(1,0), 12 ds_read + 2 gload + 16 MFMA
// per phase. NO sched_barrier/memory-clobber inside the phase (compiler may
// hoist MFMAs past lgkmcnt(0) -> read/MFMA overlap); ONE sched_barrier(0) at
// phase end pins the region ledger. Even staging, 1 half-tile/phase:
//   p1: B0(t+1)->other   [B0 other-buf last read p4(t-1), 1 barrier prior]
//   p2: A1(t+1)->other   [A1 other-buf last read p4(t-1)]
//   p3: A0(t+2)->cur     [A0 cur last read p2(t)]
//   p4: B1(t+2)->cur     [B1 cur last read p3(t)]
// Single gate vmcnt(4) at p4: FIFO ledger lands every half-tile >= 3 phases
// before its first read; 2 half-tiles always in flight (never drains to 0).

template <int ISB, int H>
__device__ __forceinline__ void stage_half(const unsigned short* __restrict__ G, int ldk,
                                           long blockBase, int k0, unsigned short* sbuf,
                                           int wid, int l) {
#pragma unroll
    for (int j = 0; j < 2; ++j) {
        int rho0;
        if (ISB) rho0 = ((wid * 8) & 31) + (wid >> 2) * 64 + H * 32 + j * 128;
        else     rho0 = wid * 8 + H * 64 + j * 128;
        int rho = rho0 + (l >> 3);
        int c = l & 7;
        const unsigned short* src =
            G + (size_t)(blockBase + rho) * ldk + k0 + ((c ^ (rho & 7)) << 3);
        gload_lds16(src, (char*)sbuf + rho0 * 128);
    }
}

#define STAGE_A0(k, buf) stage_half<0, 0>(A, K, browBase, (k), (buf), wid, l)
#define STAGE_A1(k, buf) stage_half<0, 1>(A, K, browBase, (k), (buf), wid, l)
#define STAGE_B0(k, buf) stage_half<1, 0>(B, K, bcolBase, (k), (buf), wid, l)
#define STAGE_B1(k, buf) stage_half<1, 1>(B, K, bcolBase, (k), (buf), wid, l)

#define LOAD_AF(MH)                                                                 \
    _Pragma("unroll") for (int mm = 0; mm < 4; ++mm)                                \
        _Pragma("unroll") for (int kk = 0; kk < 2; ++kk) {                          \
        int row = wr * 128 + (MH) * 64 + mm * 16 + (l & 15);                        \
        int cl = kk * 4 + (l >> 4);                                                 \
        af[mm][kk] = *(const bf16x8*)((const char*)curA + row * 128 +               \
                                      ((cl ^ (row & 7)) << 4));                     \
    }

#define LOAD_BV(NH)                                                                 \
    _Pragma("unroll") for (int nn = 0; nn < 2; ++nn)                                \
        _Pragma("unroll") for (int kk = 0; kk < 2; ++kk) {                          \
        int row = wc * 64 + (NH) * 32 + nn * 16 + (l & 15);                         \
        int cl = kk * 4 + (l >> 4);                                                 \
        bv[nn][kk] = *(const bf16x8*)((const char*)curB + row * 128 +               \
                                      ((cl ^ (row & 7)) << 4));                     \
    }

#define PHASE(MH, NH, STAGES, GATE)                                                 \
    {                                                                               \
        bf16x8 af[4][2], bv[2][2];                                                  \
        LOAD_AF(MH);                                                                \
        LOAD_BV(NH);                                                                \
        STAGES;                                                                     \
        GATE;                                                                       \
        asm volatile("s_waitcnt lgkmcnt(8)");                                       \
        __builtin_amdgcn_s_barrier();                                               \
        asm volatile("s_waitcnt lgkmcnt(0)");                                       \
        __builtin_amdgcn_s_setprio(1);                                              \
        _Pragma("unroll") for (int mm = 0; mm < 4; ++mm)                            \
            _Pragma("unroll") for (int nn = 0; nn < 2; ++nn)                        \
                _Pragma("unroll") for (int kk = 0; kk < 2; ++kk)                    \
            acc[(MH) * 4 + mm][(NH) * 2 + nn] =                                     \
                __builtin_amdgcn_mfma_f32_16x16x32_bf16(                            \
                    af[mm][kk], bv[nn][kk], acc[(MH) * 4 + mm][(NH) * 2 + nn],      \
                    0, 0, 0);                                                       \
        __builtin_amdgcn_s_setprio(0);                                              \
        __builtin_amdgcn_s_barrier();                                               \
        __builtin_amdgcn_sched_barrier(0);                                          \
    }

__global__ __launch_bounds__(512, 2) void gemm_bt256(
        const unsigned short* __restrict__ A,
        const unsigned short* __restrict__ B,
        float* __restrict__ C, int M, int N, int K) {
    __shared__ unsigned short sA[2][256 * 64];
    __shared__ unsigned short sB[2][256 * 64];
    const int tid = threadIdx.x;
    const int l = tid & 63;
    const int wid = tid >> 6;
    const int wr = wid >> 2;
    const int wc = wid & 3;

    // bijective XCD swizzle (nwg % 8 == 0); by-fastest for B-panel L2 locality
    const int nbx = N >> 8, nby = M >> 8;
    const int cpx = (nbx * nby) >> 3;
    const int swz = ((int)blockIdx.x & 7) * cpx + ((int)blockIdx.x >> 3);
    const int by = swz % nby;
    const int bx = swz / nby;
    const long browBase = (long)by << 8;
    const long bcolBase = (long)bx << 8;

    const int NT = K >> 6;

    f32x4 acc[8][4] = {};

    // prologue: tile0 (8 loads) + A0(1),B1(1) (4 loads); gate vmcnt(4) lands
    // tile0 fully, leaves A0(1),B1(1) in flight == steady-state entry shape.
    STAGE_A0(0, sA[0]);
    STAGE_B0(0, sB[0]);
    STAGE_A1(0, sA[0]);
    STAGE_B1(0, sB[0]);
    STAGE_A0(64, sA[1]);
    STAGE_B1(64, sB[1]);
    asm volatile("s_waitcnt vmcnt(4)");
    __builtin_amdgcn_s_barrier();
    __builtin_amdgcn_sched_barrier(0);

    for (int t = 0; t < NT; ++t) {
        const int cur = t & 1;
        const unsigned short* curA = sA[cur];
        const unsigned short* curB = sB[cur];
        unsigned short* oA = (unsigned short*)sA[cur ^ 1];
        unsigned short* oB = (unsigned short*)sB[cur ^ 1];
        unsigned short* cA = (unsigned short*)sA[cur];
        unsigned short* cB = (unsigned short*)sB[cur];
        // tail clamps: dummy stages land in regions already fully consumed
        // (stage follows the region's last read) and never read again.
        const int k1 = (t + 1 < NT ? t + 1 : NT - 1) << 6;
        const int k2 = (t + 2 < NT ? t + 2 : NT - 1) << 6;

        // p1: quad(0,0); stage B0(t+1) -> other
        PHASE(0, 0, { STAGE_B0(k1, oB); }, );
        // p2: quad(0,1); stage A1(t+1) -> other
        PHASE(0, 1, { STAGE_A1(k1, oA); }, );
        // p3: quad(1,1); stage A0(t+2) -> cur (A0 last read at p2)
        PHASE(1, 1, { STAGE_A0(k2, cA); }, );
        // p4: quad(1,0); stage B1(t+2) -> cur (B1 last read at p3); gate
        PHASE(1, 0, { STAGE_B1(k2, cB); },
              asm volatile("s_waitcnt vmcnt(4)"));
    }

    // drain in-flight dummy stages before this block's LDS can be reallocated
    asm volatile("s_waitcnt vmcnt(0)");

    // epilogue: C/D layout col = lane&15, row = (lane>>4)*4 + reg
    const int er = (l >> 4) * 4;
    const int ec = l & 15;
#pragma unroll
    for (int mm = 0; mm < 8; ++mm) {
#pragma unroll
        for (int nn = 0; nn < 4; ++nn) {
            long row = browBase + wr * 128 + mm * 16 + er;
            long col = bcolBase + wc * 64 + nn * 16 + ec;
            float* cp = C + row * N + col;
#pragma unroll
            for (int r = 0; r < 4; ++r)
                cp[(long)r * N] = acc[mm][nn][r];
        }
    }
}

// ---------- launch ----------
extern "C" void kernel_launch(void* const* d_in, const int* in_sizes, int n_in,
                              void* d_out, int out_size, void* d_ws, size_t ws_size,
                              hipStream_t stream) {
    const float* x = (const float*)d_in[0];
    const float* W = (const float*)d_in[1];
    float* out = (float*)d_out;

    const int K = 4096;
    const int Nout = in_sizes[1] / K;             // 4096
    const size_t Mrows = (size_t)in_sizes[0] / K; // 8192

    char* ws = (char*)d_ws;
    unsigned short* Xsp = (unsigned short*)ws;
    unsigned short* Wb = (unsigned short*)(ws + Mrows * K * 2);
    unsigned int* ma = (unsigned int*)(ws + Mrows * K * 2 + (size_t)Nout * K * 2);
    unsigned int* mw = ma + K;
    float* s = (float*)(mw + K);

    hipMemsetAsync(ma, 0, 2 * K * sizeof(unsigned int), stream);

    dim3 blk(256);
    {
        dim3 gx(K / 1024, (unsigned)(Mrows / 64));
        colmax_kernel<<<gx, blk, 0, stream>>>(x, (int)Mrows, K, ma, 64);
        dim3 gw(K / 1024, Nout / 64);
        wmaxconv_kernel<<<gw, blk, 0, stream>>>(W, mw, Wb, Nout, K, 64);
    }
    s_kernel<<<dim3((K + 255) / 256), blk, 0, stream>>>(ma, mw, s, K);
    {
        size_t ngroups = Mrows * K / 4;
        prune_kernel<<<dim3(2048), blk, 0, stream>>>(x, s, Xsp, ngroups, K);
    }
    {
        dim3 g((unsigned)((Mrows / 256) * (Nout / 256)));
        gemm_bt256<<<g, dim3(512), 0, stream>>>(Xsp, Wb, out, (int)Mrows, Nout, K);
    }
}

// Round 6
// 366.563 us; speedup vs baseline: 1.3356x; 1.3356x over previous
//
#include <hip/hip_runtime.h>
#include <hip/hip_bf16.h>

// ---------- helpers ----------

__device__ __forceinline__ unsigned short f2bf(float f) {
    unsigned u = __float_as_uint(f);
    unsigned r = u + 0x7fffu + ((u >> 16) & 1u);
    return (unsigned short)(r >> 16);
}

typedef __bf16 bf16_t;
typedef bf16_t bf16x8 __attribute__((ext_vector_type(8)));
typedef float f32x4 __attribute__((ext_vector_type(4)));

typedef const __attribute__((address_space(1))) unsigned int* gptr_t;
typedef __attribute__((address_space(3))) unsigned int* lptr_t;

__device__ __forceinline__ void gload_lds16(const void* g, void* l) {
    __builtin_amdgcn_global_load_lds((gptr_t)g, (lptr_t)l, 16, 0, 0);
}

// ---------- kernel 1: column-wise max of |x| ----------
__global__ void colmax_kernel(const float* __restrict__ src, int rows, int cols,
                              unsigned int* __restrict__ dst, int rows_per_block) {
    int c = (blockIdx.x * blockDim.x + threadIdx.x) * 4;
    if (c >= cols) return;
    int r0 = blockIdx.y * rows_per_block;
    int r1 = min(r0 + rows_per_block, rows);
    float m0 = 0.f, m1 = 0.f, m2 = 0.f, m3 = 0.f;
    const float* p = src + (size_t)r0 * cols + c;
    for (int r = r0; r < r1; ++r, p += cols) {
        float4 v = *(const float4*)p;
        m0 = fmaxf(m0, fabsf(v.x));
        m1 = fmaxf(m1, fabsf(v.y));
        m2 = fmaxf(m2, fabsf(v.z));
        m3 = fmaxf(m3, fabsf(v.w));
    }
    atomicMax(dst + c + 0, __float_as_uint(m0));
    atomicMax(dst + c + 1, __float_as_uint(m1));
    atomicMax(dst + c + 2, __float_as_uint(m2));
    atomicMax(dst + c + 3, __float_as_uint(m3));
}

// ---------- kernel 1b: fused column-max of |W| + W -> bf16 ----------
__global__ void wmaxconv_kernel(const float* __restrict__ W, unsigned int* __restrict__ mw,
                                unsigned short* __restrict__ Wb, int rows, int cols,
                                int rows_per_block) {
    int c = (blockIdx.x * blockDim.x + threadIdx.x) * 4;
    if (c >= cols) return;
    int r0 = blockIdx.y * rows_per_block;
    int r1 = min(r0 + rows_per_block, rows);
    float m0 = 0.f, m1 = 0.f, m2 = 0.f, m3 = 0.f;
    const float* p = W + (size_t)r0 * cols + c;
    unsigned short* q = Wb + (size_t)r0 * cols + c;
    for (int r = r0; r < r1; ++r, p += cols, q += cols) {
        float4 v = *(const float4*)p;
        ushort4 o;
        o.x = f2bf(v.x); o.y = f2bf(v.y); o.z = f2bf(v.z); o.w = f2bf(v.w);
        *(ushort4*)q = o;
        m0 = fmaxf(m0, fabsf(v.x));
        m1 = fmaxf(m1, fabsf(v.y));
        m2 = fmaxf(m2, fabsf(v.z));
        m3 = fmaxf(m3, fabsf(v.w));
    }
    atomicMax(mw + c + 0, __float_as_uint(m0));
    atomicMax(mw + c + 1, __float_as_uint(m1));
    atomicMax(mw + c + 2, __float_as_uint(m2));
    atomicMax(mw + c + 3, __float_as_uint(m3));
}

// ---------- kernel 2: s = sqrt(max_act / clip(max_w, EPS)) ----------
__global__ void s_kernel(const unsigned int* __restrict__ ma,
                         const unsigned int* __restrict__ mw,
                         float* __restrict__ s, int n) {
    int i = blockIdx.x * blockDim.x + threadIdx.x;
    if (i < n) {
        float a = __uint_as_float(ma[i]);
        float w = fmaxf(__uint_as_float(mw[i]), 1e-8f);
        s[i] = sqrtf(a / w);
    }
}

// ---------- kernel 3: 2:4 prune of (x/s), emit bf16(x)*mask ----------
__global__ void prune_kernel(const float* __restrict__ x, const float* __restrict__ s,
                             unsigned short* __restrict__ xsp, size_t ngroups, int cols) {
    size_t g = (size_t)blockIdx.x * blockDim.x + threadIdx.x;
    size_t stride = (size_t)gridDim.x * blockDim.x;
    for (; g < ngroups; g += stride) {
        size_t e = g * 4;
        int cb = (int)(e & (size_t)(cols - 1));
        float4 v = *(const float4*)(x + e);
        float4 sv = *(const float4*)(s + cb);
        float a0 = fabsf(v.x / sv.x);
        float a1 = fabsf(v.y / sv.y);
        float a2 = fabsf(v.z / sv.z);
        float a3 = fabsf(v.w / sv.w);
        int r0 = 0, r1 = 0, r2 = 0, r3 = 0;
        if (a1 > a0) r0++; else r1++;
        if (a2 > a0) r0++; else r2++;
        if (a3 > a0) r0++; else r3++;
        if (a2 > a1) r1++; else r2++;
        if (a3 > a1) r1++; else r3++;
        if (a3 > a2) r2++; else r3++;
        ushort4 o;
        o.x = (r0 < 2) ? f2bf(v.x) : (unsigned short)0;
        o.y = (r1 < 2) ? f2bf(v.y) : (unsigned short)0;
        o.z = (r2 < 2) ? f2bf(v.z) : (unsigned short)0;
        o.w = (r3 < 2) ? f2bf(v.w) : (unsigned short)0;
        *(ushort4*)(xsp + e) = o;
    }
}

// ---------- kernel 5: 256x256 bf16 B^T GEMM, 2 phases/K-tile, 1 barrier/phase ----------
// C[m,n] = sum_k A[m,k]*B[n,k]. 8 waves (2Mx4N), BK=64, 128 KiB LDS dbuf.
// p1: read af0(8)+bv0(4)+bv1(4); stage B0,A1(t+1)->other; barrier; 32 MFMA (quads (0,*)).
// p2: read af1(8), reuse bv; stage A0,B1(t+2)->cur (freed at p1); vmcnt(4); barrier;
//     32 MFMA (quads (1,*)).
// Ledger: every stage >= 1 barrier after its region's last LDS read; vmcnt(4)
// at p2 drains exactly tile t+1, leaves tile t+2's 4 loads in flight (never 0).

template <int ISB, int H>
__device__ __forceinline__ void stage_half(const unsigned short* __restrict__ G, int ldk,
                                           long blockBase, int k0, unsigned short* sbuf,
                                           int wid, int l) {
#pragma unroll
    for (int j = 0; j < 2; ++j) {
        int rho0;
        if (ISB) rho0 = ((wid * 8) & 31) + (wid >> 2) * 64 + H * 32 + j * 128;
        else     rho0 = wid * 8 + H * 64 + j * 128;
        int rho = rho0 + (l >> 3);
        int c = l & 7;
        const unsigned short* src =
            G + (size_t)(blockBase + rho) * ldk + k0 + ((c ^ (rho & 7)) << 3);
        gload_lds16(src, (char*)sbuf + rho0 * 128);
    }
}

#define STAGE_A0(k, buf) stage_half<0, 0>(A, K, browBase, (k), (buf), wid, l)
#define STAGE_A1(k, buf) stage_half<0, 1>(A, K, browBase, (k), (buf), wid, l)
#define STAGE_B0(k, buf) stage_half<1, 0>(B, K, bcolBase, (k), (buf), wid, l)
#define STAGE_B1(k, buf) stage_half<1, 1>(B, K, bcolBase, (k), (buf), wid, l)

#define LOAD_AF(MH)                                                                 \
    _Pragma("unroll") for (int mm = 0; mm < 4; ++mm)                                \
        _Pragma("unroll") for (int kk = 0; kk < 2; ++kk) {                          \
        int row = wr * 128 + (MH) * 64 + mm * 16 + (l & 15);                        \
        int cl = kk * 4 + (l >> 4);                                                 \
        af[mm][kk] = *(const bf16x8*)((const char*)curA + row * 128 +               \
                                      ((cl ^ (row & 7)) << 4));                     \
    }

#define LOAD_BV(dst, NH)                                                            \
    _Pragma("unroll") for (int nn = 0; nn < 2; ++nn)                                \
        _Pragma("unroll") for (int kk = 0; kk < 2; ++kk) {                          \
        int row = wc * 64 + (NH) * 32 + nn * 16 + (l & 15);                         \
        int cl = kk * 4 + (l >> 4);                                                 \
        dst[nn][kk] = *(const bf16x8*)((const char*)curB + row * 128 +              \
                                       ((cl ^ (row & 7)) << 4));                    \
    }

#define MFMA_HALF(MH)                                                               \
    __builtin_amdgcn_s_setprio(1);                                                  \
    _Pragma("unroll") for (int mm = 0; mm < 4; ++mm)                                \
        _Pragma("unroll") for (int nn = 0; nn < 2; ++nn)                            \
            _Pragma("unroll") for (int kk = 0; kk < 2; ++kk) {                      \
        acc[(MH) * 4 + mm][nn] = __builtin_amdgcn_mfma_f32_16x16x32_bf16(           \
            af[mm][kk], bv0[nn][kk], acc[(MH) * 4 + mm][nn], 0, 0, 0);              \
        acc[(MH) * 4 + mm][2 + nn] = __builtin_amdgcn_mfma_f32_16x16x32_bf16(       \
            af[mm][kk], bv1[nn][kk], acc[(MH) * 4 + mm][2 + nn], 0, 0, 0);          \
    }                                                                               \
    __builtin_amdgcn_s_setprio(0);                                                  \
    __builtin_amdgcn_sched_barrier(0);

__global__ __launch_bounds__(512, 2) void gemm_bt256(
        const unsigned short* __restrict__ A,
        const unsigned short* __restrict__ B,
        float* __restrict__ C, int M, int N, int K) {
    __shared__ unsigned short sA[2][256 * 64];
    __shared__ unsigned short sB[2][256 * 64];
    const int tid = threadIdx.x;
    const int l = tid & 63;
    const int wid = tid >> 6;
    const int wr = wid >> 2;
    const int wc = wid & 3;

    // bijective XCD swizzle (nwg % 8 == 0); by-fastest for B-panel L2 locality
    const int nbx = N >> 8, nby = M >> 8;
    const int cpx = (nbx * nby) >> 3;
    const int swz = ((int)blockIdx.x & 7) * cpx + ((int)blockIdx.x >> 3);
    const int by = swz % nby;
    const int bx = swz / nby;
    const long browBase = (long)by << 8;
    const long bcolBase = (long)bx << 8;

    const int NT = K >> 6;

    f32x4 acc[8][4] = {};

    // prologue: tile0 (8 loads) + A0(1),B1(1) (4 loads); vmcnt(4) drains tile0,
    // leaves A0(1),B1(1) in flight == steady-state entry shape.
    STAGE_A0(0, sA[0]);
    STAGE_B0(0, sB[0]);
    STAGE_B1(0, sB[0]);
    STAGE_A1(0, sA[0]);
    STAGE_A0(64, sA[1]);
    STAGE_B1(64, sB[1]);
    asm volatile("s_waitcnt vmcnt(4)" ::: "memory");
    __builtin_amdgcn_s_barrier();
    __builtin_amdgcn_sched_barrier(0);

    for (int t = 0; t < NT; ++t) {
        const int cur = t & 1;
        const unsigned short* curA = sA[cur];
        const unsigned short* curB = sB[cur];
        unsigned short* oA = (unsigned short*)sA[cur ^ 1];
        unsigned short* oB = (unsigned short*)sB[cur ^ 1];
        unsigned short* cA = (unsigned short*)sA[cur];
        unsigned short* cB = (unsigned short*)sB[cur];
        // tail clamps: dummy re-stages land in regions already consumed and
        // never read again; keeps the vmcnt FIFO ledger uniform.
        const int k1 = (t + 1 < NT ? t + 1 : NT - 1) << 6;
        const int k2 = (t + 2 < NT ? t + 2 : NT - 1) << 6;

        bf16x8 af[4][2], bv0[2][2], bv1[2][2];

        // ---- phase 1: quads (0,0)+(0,1) ----
        LOAD_AF(0);
        LOAD_BV(bv0, 0);
        LOAD_BV(bv1, 1);
        STAGE_B0(k1, oB);
        STAGE_A1(k1, oA);
        asm volatile("s_waitcnt lgkmcnt(8)" ::: "memory");
        __builtin_amdgcn_s_barrier();
        asm volatile("s_waitcnt lgkmcnt(0)" ::: "memory");
        __builtin_amdgcn_sched_barrier(0);
        MFMA_HALF(0);

        // ---- phase 2: quads (1,1)+(1,0), bv reused from registers ----
        LOAD_AF(1);
        STAGE_A0(k2, cA);
        STAGE_B1(k2, cB);
        asm volatile("s_waitcnt vmcnt(4)" ::: "memory");
        __builtin_amdgcn_s_barrier();
        asm volatile("s_waitcnt lgkmcnt(0)" ::: "memory");
        __builtin_amdgcn_sched_barrier(0);
        MFMA_HALF(1);
    }

    // drain in-flight dummy stages before LDS could be reallocated
    asm volatile("s_waitcnt vmcnt(0)" ::: "memory");

    // epilogue: C/D layout col = lane&15, row = (lane>>4)*4 + reg
    const int er = (l >> 4) * 4;
    const int ec = l & 15;
#pragma unroll
    for (int mm = 0; mm < 8; ++mm) {
#pragma unroll
        for (int nn = 0; nn < 4; ++nn) {
            long row = browBase + wr * 128 + mm * 16 + er;
            long col = bcolBase + wc * 64 + nn * 16 + ec;
            float* cp = C + row * N + col;
#pragma unroll
            for (int r = 0; r < 4; ++r)
                cp[(long)r * N] = acc[mm][nn][r];
        }
    }
}

// ---------- launch ----------
extern "C" void kernel_launch(void* const* d_in, const int* in_sizes, int n_in,
                              void* d_out, int out_size, void* d_ws, size_t ws_size,
                              hipStream_t stream) {
    const float* x = (const float*)d_in[0];
    const float* W = (const float*)d_in[1];
    float* out = (float*)d_out;

    const int K = 4096;
    const int Nout = in_sizes[1] / K;             // 4096
    const size_t Mrows = (size_t)in_sizes[0] / K; // 8192

    char* ws = (char*)d_ws;
    unsigned short* Xsp = (unsigned short*)ws;
    unsigned short* Wb = (unsigned short*)(ws + Mrows * K * 2);
    unsigned int* ma = (unsigned int*)(ws + Mrows * K * 2 + (size_t)Nout * K * 2);
    unsigned int* mw = ma + K;
    float* s = (float*)(mw + K);

    hipMemsetAsync(ma, 0, 2 * K * sizeof(unsigned int), stream);

    dim3 blk(256);
    {
        dim3 gx(K / 1024, (unsigned)(Mrows / 64));
        colmax_kernel<<<gx, blk, 0, stream>>>(x, (int)Mrows, K, ma, 64);
        dim3 gw(K / 1024, Nout / 64);
        wmaxconv_kernel<<<gw, blk, 0, stream>>>(W, mw, Wb, Nout, K, 64);
    }
    s_kernel<<<dim3((K + 255) / 256), blk, 0, stream>>>(ma, mw, s, K);
    {
        size_t ngroups = Mrows * K / 4;
        prune_kernel<<<dim3(2048), blk, 0, stream>>>(x, s, Xsp, ngroups, K);
    }
    {
        dim3 g((unsigned)((Mrows / 256) * (Nout / 256)));
        gemm_bt256<<<g, dim3(512), 0, stream>>>(Xsp, Wb, out, (int)Mrows, Nout, K);
    }
}